// Round 3
// baseline (251.480 us; speedup 1.0000x reference)
//
#include <hip/hip_runtime.h>

#define N_NODES 10000
#define N_EDGES 320000
#define DIM_IN  512
#define DIM_HID 128
#define HC      256   // HEADS*GC
#define NEG_SLOPE 0.2f

// ---------------------------------------------------------------------------
// Tiled fp32 GEMM: C[M,N] = act(A[M,K] @ B[K,N] + bias)
// BN=64, BK=16, 256 threads. BM=64 -> 4x4 micro; BM=32 -> 2x4 micro (twice
// the blocks, for occupancy on skinny-N GEMMs).
// A tile transposed [BK][BM+4] -> conflict-free LDS vector reads.
// ATT: fused attention-score epilogue (one head per block since BN==64):
//   a_src[row,h] = sum_c acc_row[c]*att_src[h,c]; width-16 shfl reduce.
// ---------------------------------------------------------------------------
template<int BM, bool RELU, bool BIAS, bool ATT>
__global__ __launch_bounds__(256) void gemm_kernel(
    const float* __restrict__ A, const float* __restrict__ B,
    const float* __restrict__ bias, float* __restrict__ C,
    int M, int N, int K,
    const float* __restrict__ att_src, const float* __restrict__ att_dst,
    float* __restrict__ a_src, float* __restrict__ a_dst) {
  constexpr int BN = 64, BK = 16;
  constexpr int RPT = BM / 16;           // rows per thread (4 or 2)
  __shared__ float Ast[BK][BM + 4];
  __shared__ float Bs[BK][BN];
  const int t  = threadIdx.x;
  const int tx = t & 15, ty = t >> 4;
  const int m0 = blockIdx.x * BM, n0 = blockIdx.y * BN;
  const int ar = t >> 2, ac4 = (t & 3) * 4;   // A loader: row, k-offset
  const int br = t >> 4, bc4 = (t & 15) * 4;  // B loader: k-row, col-offset
  float acc[RPT][4] = {};
  const int  arow  = m0 + ar;
  const bool aldr  = (t < BM * 4);            // threads participating in A load
  const float* Aptr = A + (size_t)arow * K + ac4;
  const float* Bptr = B + (size_t)br * N + n0 + bc4;

  for (int k0 = 0; k0 < K; k0 += BK) {
    float4 av = make_float4(0.f, 0.f, 0.f, 0.f);
    if (aldr && arow < M) av = *(const float4*)(Aptr + k0);
    const float4 bv = *(const float4*)(Bptr + (size_t)k0 * N);
    if (aldr) {
      Ast[ac4 + 0][ar] = av.x; Ast[ac4 + 1][ar] = av.y;
      Ast[ac4 + 2][ar] = av.z; Ast[ac4 + 3][ar] = av.w;
    }
    *(float4*)&Bs[br][bc4] = bv;
    __syncthreads();
#pragma unroll
    for (int kk = 0; kk < BK; ++kk) {
      float as[RPT];
#pragma unroll
      for (int i = 0; i < RPT; ++i) as[i] = Ast[kk][ty * RPT + i];
      const float4 b = *(const float4*)&Bs[kk][tx * 4];
      const float bs[4] = {b.x, b.y, b.z, b.w};
#pragma unroll
      for (int i = 0; i < RPT; ++i)
#pragma unroll
        for (int j = 0; j < 4; ++j) acc[i][j] = fmaf(as[i], bs[j], acc[i][j]);
    }
    __syncthreads();
  }

  float4 bvv = make_float4(0.f, 0.f, 0.f, 0.f);
  if (BIAS) bvv = *(const float4*)(bias + n0 + tx * 4);
#pragma unroll
  for (int i = 0; i < RPT; ++i) {
    const int row = m0 + ty * RPT + i;
    if (row < M) {
      float4 v;
      v.x = acc[i][0] + bvv.x; v.y = acc[i][1] + bvv.y;
      v.z = acc[i][2] + bvv.z; v.w = acc[i][3] + bvv.w;
      if (RELU) {
        v.x = fmaxf(v.x, 0.f); v.y = fmaxf(v.y, 0.f);
        v.z = fmaxf(v.z, 0.f); v.w = fmaxf(v.w, 0.f);
      }
      *(float4*)(C + (size_t)row * N + n0 + tx * 4) = v;
    }
  }

  if (ATT) {
    // this block's columns are exactly head hh = n0/64, in-head chan = tx*4+j
    const int hh = n0 >> 6;
#pragma unroll
    for (int i = 0; i < RPT; ++i) {
      float ps = 0.f, pd = 0.f;
#pragma unroll
      for (int j = 0; j < 4; ++j) {
        const int c = tx * 4 + j;
        ps = fmaf(acc[i][j], att_src[hh * 64 + c], ps);
        pd = fmaf(acc[i][j], att_dst[hh * 64 + c], pd);
      }
#pragma unroll
      for (int off = 8; off > 0; off >>= 1) {
        ps += __shfl_down(ps, off, 16);
        pd += __shfl_down(pd, off, 16);
      }
      if (tx == 0) {
        const int row = m0 + ty * RPT + i;
        if (row < M) {
          a_src[row * 4 + hh] = ps;
          a_dst[row * 4 + hh] = pd;
        }
      }
    }
  }
}

// bfuse[c] = sum_k b2[k] * Wg[k,c]   (one 256-thread block, coalesced)
__global__ __launch_bounds__(256) void bias_fuse_kernel(
    const float* __restrict__ b2, const float* __restrict__ Wg,
    float* __restrict__ bfuse) {
  const int c = threadIdx.x;
  float acc = 0.f;
  for (int k = 0; k < DIM_HID; ++k) acc = fmaf(b2[k], Wg[k * HC + c], acc);
  bfuse[c] = acc;
}

// ---------------------------------------------------------------------------
// CSR build: histogram of dst (E real edges + N self loops)
// ---------------------------------------------------------------------------
__global__ __launch_bounds__(256) void hist_kernel(
    const int* __restrict__ dst_arr, int* __restrict__ count) {
  const int id = blockIdx.x * 256 + threadIdx.x;
  if (id < N_EDGES)                 atomicAdd(&count[dst_arr[id]], 1);
  else if (id < N_EDGES + N_NODES)  atomicAdd(&count[id - N_EDGES], 1);
}

// Work-efficient single-block scan: 256 threads x 40 sequential elements,
// 8-step LDS scan of the 256 partials.
__global__ __launch_bounds__(256) void scan_kernel(
    const int* __restrict__ count, int* __restrict__ offsets,
    int* __restrict__ cursor, int n) {
  constexpr int PER = 40;  // 256*40 = 10240 >= 10000
  __shared__ int sums[256];
  const int t = threadIdx.x;
  const int base = t * PER;
  int loc[PER];
  int s = 0;
#pragma unroll
  for (int k = 0; k < PER; ++k) {
    const int i = base + k;
    const int v = (i < n) ? count[i] : 0;
    loc[k] = s;  // local exclusive prefix
    s += v;
  }
  sums[t] = s;
  __syncthreads();
#pragma unroll
  for (int off = 1; off < 256; off <<= 1) {
    const int add = (t >= off) ? sums[t - off] : 0;
    __syncthreads();
    sums[t] += add;
    __syncthreads();
  }
  const int carry = (t == 0) ? 0 : sums[t - 1];
#pragma unroll
  for (int k = 0; k < PER; ++k) {
    const int i = base + k;
    if (i < n) {
      const int o = carry + loc[k];
      offsets[i] = o;
      cursor[i]  = o;
    }
  }
  if (t == 255) offsets[n] = sums[255];
}

__global__ __launch_bounds__(256) void scatter_kernel(
    const int* __restrict__ src_arr, const int* __restrict__ dst_arr,
    int* __restrict__ cursor, int* __restrict__ src_sorted) {
  const int id = blockIdx.x * 256 + threadIdx.x;
  int s, d;
  if (id < N_EDGES)                { s = src_arr[id]; d = dst_arr[id]; }
  else if (id < N_EDGES + N_NODES) { s = d = id - N_EDGES; }
  else return;
  const int pos = atomicAdd(&cursor[d], 1);
  src_sorted[pos] = s;
}

// ---------------------------------------------------------------------------
// One block (256 thr) per destination node. alpha = exp(leaky(e))/sum —
// max-shift removable since |e| is small and bounded. Per 256-edge chunk:
// stage src idx + cooperative exp(w) into LDS, then each thread (head=t>>6,
// chan=t&63) accumulates w*g[src,t] with coalesced 1KB row gathers.
// ---------------------------------------------------------------------------
__global__ __launch_bounds__(256) void aggregate_kernel(
    const float* __restrict__ g, const float* __restrict__ a_src,
    const float* __restrict__ a_dst, const int* __restrict__ offsets,
    const int* __restrict__ src_sorted, const float* __restrict__ bias_g,
    float* __restrict__ out) {
  const int i = blockIdx.x;
  const int t = threadIdx.x;
  const int start = offsets[i], end = offsets[i + 1];
  const int h = t >> 6;
  __shared__ float f_adst[4];
  __shared__ int   sidx_buf[256];
  __shared__ float w_buf[256 * 4];
  if (t < 4) f_adst[t] = a_dst[i * 4 + t];
  __syncthreads();
  const int   hh      = t & 3;
  const float adst_hh = f_adst[hh];
  const float* gt = g + t;

  float acc = 0.f, s_loc = 0.f;
  for (int cbase = start; cbase < end; cbase += 256) {
    const int cnt = min(256, end - cbase);
    if (t < cnt) sidx_buf[t] = src_sorted[cbase + t];
    __syncthreads();
    for (int jj = t >> 2; jj < cnt; jj += 64) {
      float e = a_src[sidx_buf[jj] * 4 + hh] + adst_hh;
      e = (e > 0.f) ? e : NEG_SLOPE * e;
      w_buf[jj * 4 + hh] = __expf(e);
    }
    __syncthreads();
#pragma unroll 4
    for (int jj = 0; jj < cnt; ++jj) {
      const float w = w_buf[jj * 4 + h];          // LDS broadcast
      s_loc += w;
      acc = fmaf(w, gt[(size_t)sidx_buf[jj] * HC], acc);
    }
    __syncthreads();  // protect LDS bufs before next chunk overwrites
  }
  out[(size_t)i * HC + t] = acc / s_loc + bias_g[t];
}

// ---------------------------------------------------------------------------
extern "C" void kernel_launch(void* const* d_in, const int* in_sizes, int n_in,
                              void* d_out, int out_size, void* d_ws, size_t ws_size,
                              hipStream_t stream) {
  const float* x       = (const float*)d_in[0];
  const int*   ei      = (const int*)d_in[1];   // [2,E] int32: src then dst
  const float* W1      = (const float*)d_in[2];
  const float* b1      = (const float*)d_in[3];
  const float* W2      = (const float*)d_in[4];
  const float* b2      = (const float*)d_in[5];
  const float* Wg      = (const float*)d_in[6];
  const float* att_src = (const float*)d_in[7];
  const float* att_dst = (const float*)d_in[8];
  const float* bias_g  = (const float*)d_in[9];
  float* out = (float*)d_out;

  char* ws = (char*)d_ws;
  float* h1      = (float*)ws; ws += (size_t)N_NODES * DIM_HID * 4;
  float* g       = (float*)ws; ws += (size_t)N_NODES * HC * 4;
  float* Wfuse   = (float*)ws; ws += (size_t)DIM_HID * HC * 4;
  float* bfuse   = (float*)ws; ws += (size_t)HC * 4;
  float* a_src   = (float*)ws; ws += (size_t)N_NODES * 4 * 4;
  float* a_dst   = (float*)ws; ws += (size_t)N_NODES * 4 * 4;
  int* count     = (int*)ws;   ws += (size_t)N_NODES * 4;
  int* offsets   = (int*)ws;   ws += (size_t)(N_NODES + 4) * 4;
  int* cursor    = (int*)ws;   ws += (size_t)N_NODES * 4;
  int* src_sorted= (int*)ws;   ws += (size_t)(N_EDGES + N_NODES) * 4;

  hipMemsetAsync(count, 0, N_NODES * sizeof(int), stream);

  const dim3 blk(256);
  // tiny weight pre-fusion: Wfuse = W2 @ Wg, bfuse = b2 @ Wg
  gemm_kernel<64, false, false, false><<<dim3(2, 4), blk, 0, stream>>>(
      W2, Wg, nullptr, Wfuse, DIM_HID, HC, DIM_HID, nullptr, nullptr, nullptr, nullptr);
  bias_fuse_kernel<<<1, 256, 0, stream>>>(b2, Wg, bfuse);
  // encoder layer 1 (BM=32 -> 626 blocks for occupancy)
  gemm_kernel<32, true, true, false><<<dim3(313, 2), blk, 0, stream>>>(
      x, W1, b1, h1, N_NODES, DIM_HID, DIM_IN, nullptr, nullptr, nullptr, nullptr);
  // fused encoder layer 2 + GAT linear, with attention-score epilogue
  gemm_kernel<64, false, true, true><<<dim3(157, 4), blk, 0, stream>>>(
      h1, Wfuse, bfuse, g, N_NODES, HC, DIM_HID, att_src, att_dst, a_src, a_dst);
  // CSR build (E edges + N self loops), bucketed by destination
  const int nEdgeBlk = (N_EDGES + N_NODES + 255) / 256;
  hist_kernel   <<<nEdgeBlk, blk, 0, stream>>>(ei + N_EDGES, count);
  scan_kernel   <<<1, 256, 0, stream>>>(count, offsets, cursor, N_NODES);
  scatter_kernel<<<nEdgeBlk, blk, 0, stream>>>(ei, ei + N_EDGES, cursor, src_sorted);
  // segment softmax + weighted aggregate, one block per node
  aggregate_kernel<<<N_NODES, blk, 0, stream>>>(g, a_src, a_dst, offsets, src_sorted, bias_g, out);
}